// Round 1
// baseline (319.361 us; speedup 1.0000x reference)
//
#include <hip/hip_runtime.h>
#include <math.h>

#define H_ 192
#define W_ 192
#define HW_ (H_*W_)      // 36864
#define B_ 2
#define C_ 64
#define NPIX_ (B_*HW_)   // 73728
#define EPSV 1e-5f

// ---------------------------------------------------------------------------
// Fold: w1t[c][o] = w1[o][c];  wk[k][c][p] = sum_o w2[p,o]*dw[o,c,k];
//       beff[p]  = sum_o w2[p,o]*db[o] + b2[p]
// ---------------------------------------------------------------------------
__global__ void k_fold(const float* __restrict__ w1, const float* __restrict__ w2,
                       const float* __restrict__ dw, const float* __restrict__ db,
                       const float* __restrict__ b2,
                       float* __restrict__ w1t, float* __restrict__ wk,
                       float* __restrict__ beff)
{
    int tid = blockIdx.x * 256 + threadIdx.x;   // 0..36863
    if (tid < 9 * 64 * 64) {
        int k = tid >> 12;
        int r = tid & 4095;
        int c = r >> 6;
        int p = r & 63;
        float acc = 0.f;
        #pragma unroll 8
        for (int o = 0; o < 64; ++o)
            acc = fmaf(w2[p * 64 + o], dw[(o * 64 + c) * 9 + k], acc);
        wk[tid] = acc;
    }
    if (tid < 4096) {
        int c = tid >> 6, o = tid & 63;
        w1t[c * 64 + o] = w1[o * 64 + c];
    }
    if (tid < 64) {
        float acc = b2[tid];
        #pragma unroll 8
        for (int o = 0; o < 64; ++o) acc = fmaf(w2[tid * 64 + o], db[o], acc);
        beff[tid] = acc;
    }
}

// ---------------------------------------------------------------------------
// conv1x1 #1: y[b,o,hw] = sum_c x[b,c,hw]*w1t[c][o] + b1[o]
// block = 64 pixels x 64 out-channels, 256 threads, 4px x 4oc per thread
// ---------------------------------------------------------------------------
__global__ __launch_bounds__(256) void k_conv1x1(const float* __restrict__ x,
        const float* __restrict__ w1t, const float* __restrict__ b1,
        float* __restrict__ y)
{
    __shared__ __align__(16) float xs[64][64];   // [c][p]
    __shared__ __align__(16) float wsh[64][64];  // [c][o]
    int t = threadIdx.x;
    int base = blockIdx.x * 64;
    int b = base / HW_;
    int hw0 = base % HW_;

    #pragma unroll
    for (int i = 0; i < 16; ++i) {
        int e = t + i * 256;
        ((float*)wsh)[e] = w1t[e];
    }
    int p = t & 63, cg = t >> 6;
    #pragma unroll
    for (int i = 0; i < 16; ++i) {
        int c = cg * 16 + i;
        xs[c][p] = x[(b * 64 + c) * HW_ + hw0 + p];
    }
    __syncthreads();

    int l = t & 63, wv = t >> 6;
    int pg = l & 15;
    int og = wv * 4 + (l >> 4);
    float acc[4][4];
    #pragma unroll
    for (int i = 0; i < 4; ++i)
        #pragma unroll
        for (int j = 0; j < 4; ++j) acc[i][j] = 0.f;

    #pragma unroll 8
    for (int c = 0; c < 64; ++c) {
        float va[4], wa[4];
        *(float4*)va = *(const float4*)&xs[c][pg * 4];
        *(float4*)wa = *(const float4*)&wsh[c][og * 4];
        #pragma unroll
        for (int i = 0; i < 4; ++i)
            #pragma unroll
            for (int j = 0; j < 4; ++j)
                acc[i][j] = fmaf(va[i], wa[j], acc[i][j]);
    }

    #pragma unroll
    for (int j = 0; j < 4; ++j) {
        int oc = og * 4 + j;
        float bias = b1[oc];
        float4 o4 = make_float4(acc[0][j] + bias, acc[1][j] + bias,
                                acc[2][j] + bias, acc[3][j] + bias);
        *(float4*)&y[(b * 64 + oc) * HW_ + hw0 + pg * 4] = o4;
    }
}

// ---------------------------------------------------------------------------
// BN stats: one block per channel; writes scale, shift
// ---------------------------------------------------------------------------
__global__ void k_stats(const float* __restrict__ y, const float* __restrict__ g,
                        const float* __restrict__ be, float* __restrict__ scsh)
{
    int c = blockIdx.x;
    int t = threadIdx.x;
    float s = 0.f, sq = 0.f;
    for (int b = 0; b < B_; ++b) {
        const float4* p4 = (const float4*)&y[(b * 64 + c) * HW_];
        for (int i = t; i < HW_ / 4; i += 256) {
            float4 v = p4[i];
            s += v.x + v.y + v.z + v.w;
            sq += v.x * v.x + v.y * v.y + v.z * v.z + v.w * v.w;
        }
    }
    int lane = t & 63, wv = t >> 6;
    #pragma unroll
    for (int off = 32; off > 0; off >>= 1) {
        s += __shfl_down(s, off);
        sq += __shfl_down(sq, off);
    }
    __shared__ float red[8];
    if (lane == 0) { red[wv] = s; red[4 + wv] = sq; }
    __syncthreads();
    if (t == 0) {
        float S = red[0] + red[1] + red[2] + red[3];
        float Q = red[4] + red[5] + red[6] + red[7];
        float m = S / (float)NPIX_;
        float var = Q / (float)NPIX_ - m * m;
        float sc = g[c] * rsqrtf(var + EPSV);
        scsh[c] = sc;
        scsh[64 + c] = be[c] - m * sc;
    }
}

// ---------------------------------------------------------------------------
// BN apply (optional ReLU), in place, float4
// ---------------------------------------------------------------------------
__global__ void k_bn(float* __restrict__ y, const float* __restrict__ scsh, int relu)
{
    int idx = blockIdx.x * 256 + threadIdx.x;         // float4 index
    int c = ((idx * 4) / HW_) & 63;
    float sc = scsh[c], sh = scsh[64 + c];
    float4 v = ((float4*)y)[idx];
    v.x = fmaf(v.x, sc, sh);
    v.y = fmaf(v.y, sc, sh);
    v.z = fmaf(v.z, sc, sh);
    v.w = fmaf(v.w, sc, sh);
    if (relu) {
        v.x = fmaxf(v.x, 0.f); v.y = fmaxf(v.y, 0.f);
        v.z = fmaxf(v.z, 0.f); v.w = fmaxf(v.w, 0.f);
    }
    ((float4*)y)[idx] = v;
}

// ---------------------------------------------------------------------------
// offset conv3x3: A[b,64,H,W] -> off[b,18,H,W], zero pad 1
// block = 16x16 spatial tile; 4 channel-chunks of 16 staged in LDS
// ---------------------------------------------------------------------------
__global__ __launch_bounds__(256) void k_offconv(const float* __restrict__ A,
        const float* __restrict__ ow, const float* __restrict__ ob,
        float* __restrict__ off)
{
    __shared__ float As[16 * 18 * 18];   // [c][r][col]
    __shared__ float wsh[16 * 9 * 20];   // [c][tap][oc pad20]
    int t = threadIdx.x;
    int bid = blockIdx.x;
    int b = bid / 144;
    int tile = bid % 144;
    int ty = tile / 12, tx = tile % 12;
    int y0 = ty * 16, x0 = tx * 16;
    int lx = t & 15, ly = t >> 4;

    float acc[18];
    #pragma unroll
    for (int i = 0; i < 18; ++i) acc[i] = 0.f;

    for (int cg = 0; cg < 4; ++cg) {
        int c0 = cg * 16;
        __syncthreads();
        for (int e = t; e < 16 * 18 * 18; e += 256) {
            int c = e / 324, rem = e % 324;
            int r = rem / 18, col = rem % 18;
            int gy = y0 - 1 + r, gx = x0 - 1 + col;
            float v = 0.f;
            if (gy >= 0 && gy < H_ && gx >= 0 && gx < W_)
                v = A[(b * 64 + c0 + c) * HW_ + gy * W_ + gx];
            As[e] = v;
        }
        for (int e = t; e < 16 * 9 * 18; e += 256) {
            int c = e / 162, rem = e % 162;
            int tap = rem / 18, oc = rem % 18;
            wsh[(c * 9 + tap) * 20 + oc] = ow[((oc * 64) + c0 + c) * 9 + tap];
        }
        __syncthreads();
        for (int c = 0; c < 16; ++c) {
            #pragma unroll
            for (int tap = 0; tap < 9; ++tap) {
                int ky = tap / 3, kx = tap % 3;
                float a = As[c * 324 + (ly + ky) * 18 + (lx + kx)];
                const float* wr = &wsh[(c * 9 + tap) * 20];
                #pragma unroll
                for (int oc = 0; oc < 18; ++oc)
                    acc[oc] = fmaf(a, wr[oc], acc[oc]);
            }
        }
    }
    #pragma unroll
    for (int oc = 0; oc < 18; ++oc)
        off[(b * 18 + oc) * HW_ + (y0 + ly) * W_ + x0 + lx] = acc[oc] + ob[oc];
}

// ---------------------------------------------------------------------------
// deformable conv with folded conv1x1: out[b,p,hw] via wk[k][c][p], beff
// block = 64 pixels (one row segment) x 64 out-channels
// ---------------------------------------------------------------------------
__global__ __launch_bounds__(256) void k_deform(const float* __restrict__ A,
        const float* __restrict__ off, const float* __restrict__ wk,
        const float* __restrict__ beff, float* __restrict__ out)
{
    __shared__ __align__(16) float vs[64][64];   // [c][p]
    __shared__ __align__(16) float wsh[64][64];  // [c][o]
    int t = threadIdx.x;
    int base = blockIdx.x * 64;
    int b = base / HW_;
    int hw0 = base % HW_;
    int h = hw0 / W_;
    int w0 = hw0 % W_;

    int p = t & 63, cg = t >> 6;
    int l = t & 63, wv = t >> 6;
    int pg = l & 15, og = wv * 4 + (l >> 4);

    float acc[4][4];
    #pragma unroll
    for (int i = 0; i < 4; ++i)
        #pragma unroll
        for (int j = 0; j < 4; ++j) acc[i][j] = 0.f;

    for (int k = 0; k < 9; ++k) {
        __syncthreads();   // protect previous iteration's LDS reads
        // stage folded weights for this tap
        #pragma unroll
        for (int i = 0; i < 16; ++i) {
            int e = t + i * 256;
            ((float*)wsh)[e] = wk[k * 4096 + e];
        }
        // bilinear gather for this tap: thread owns pixel p, 16 channels
        float dy = off[((b * 18) + 2 * k) * HW_ + hw0 + p];
        float dx = off[((b * 18) + 2 * k + 1) * HW_ + hw0 + p];
        float py = (float)(h + k / 3 - 1) + dy;
        float px = (float)(w0 + p + k % 3 - 1) + dx;
        float fly = floorf(py), flx = floorf(px);
        float fy = py - fly, fx = px - flx;
        int y0i = (int)fly, x0i = (int)flx;
        float w00 = (1.f - fy) * (1.f - fx);
        float w01 = (1.f - fy) * fx;
        float w10 = fy * (1.f - fx);
        float w11 = fy * fx;
        bool yv0 = (y0i >= 0) && (y0i < H_);
        bool yv1 = (y0i + 1 >= 0) && (y0i + 1 < H_);
        bool xv0 = (x0i >= 0) && (x0i < W_);
        bool xv1 = (x0i + 1 >= 0) && (x0i + 1 < W_);
        if (!(yv0 && xv0)) w00 = 0.f;
        if (!(yv0 && xv1)) w01 = 0.f;
        if (!(yv1 && xv0)) w10 = 0.f;
        if (!(yv1 && xv1)) w11 = 0.f;
        int yc0 = min(max(y0i, 0), H_ - 1), yc1 = min(max(y0i + 1, 0), H_ - 1);
        int xc0 = min(max(x0i, 0), W_ - 1), xc1 = min(max(x0i + 1, 0), W_ - 1);
        int i00 = yc0 * W_ + xc0, i01 = yc0 * W_ + xc1;
        int i10 = yc1 * W_ + xc0, i11 = yc1 * W_ + xc1;

        const float* Ab = &A[(b * 64 + cg * 16) * HW_];
        #pragma unroll
        for (int i = 0; i < 16; ++i) {
            float v = Ab[i00] * w00 + Ab[i01] * w01 + Ab[i10] * w10 + Ab[i11] * w11;
            vs[cg * 16 + i][p] = v;
            Ab += HW_;
        }
        __syncthreads();
        // 64px x 64oc matmul for this tap
        #pragma unroll 8
        for (int c = 0; c < 64; ++c) {
            float va[4], wa[4];
            *(float4*)va = *(const float4*)&vs[c][pg * 4];
            *(float4*)wa = *(const float4*)&wsh[c][og * 4];
            #pragma unroll
            for (int i = 0; i < 4; ++i)
                #pragma unroll
                for (int j = 0; j < 4; ++j)
                    acc[i][j] = fmaf(va[i], wa[j], acc[i][j]);
        }
    }

    #pragma unroll
    for (int j = 0; j < 4; ++j) {
        int oc = og * 4 + j;
        float bias = beff[oc];
        float4 o4 = make_float4(acc[0][j] + bias, acc[1][j] + bias,
                                acc[2][j] + bias, acc[3][j] + bias);
        *(float4*)&out[(b * 64 + oc) * HW_ + hw0 + pg * 4] = o4;
    }
}

// ---------------------------------------------------------------------------
extern "C" void kernel_launch(void* const* d_in, const int* in_sizes, int n_in,
                              void* d_out, int out_size, void* d_ws, size_t ws_size,
                              hipStream_t stream)
{
    const float* x   = (const float*)d_in[0];
    const float* w1  = (const float*)d_in[1];
    const float* b1  = (const float*)d_in[2];
    const float* g1  = (const float*)d_in[3];
    const float* be1 = (const float*)d_in[4];
    const float* ow  = (const float*)d_in[5];
    const float* ob  = (const float*)d_in[6];
    const float* dw  = (const float*)d_in[7];
    const float* db  = (const float*)d_in[8];
    const float* w2  = (const float*)d_in[9];
    const float* b2  = (const float*)d_in[10];
    const float* g2  = (const float*)d_in[11];
    const float* be2 = (const float*)d_in[12];
    float* out = (float*)d_out;

    float* ws    = (float*)d_ws;
    float* A     = ws;                       // 4,718,592 floats (y1 then A in place)
    float* offb  = A + (size_t)NPIX_ * 64;   // 1,327,104 floats
    float* w1t   = offb + (size_t)B_ * 18 * HW_;
    float* wk    = w1t + 4096;               // 36,864 floats
    float* beff  = wk + 9 * 4096;            // 64
    float* scsh1 = beff + 64;                // 128
    float* scsh2 = scsh1 + 128;              // 128

    hipLaunchKernelGGL(k_fold, dim3(144), dim3(256), 0, stream,
                       w1, w2, dw, db, b2, w1t, wk, beff);
    hipLaunchKernelGGL(k_conv1x1, dim3(NPIX_ / 64), dim3(256), 0, stream,
                       x, w1t, b1, A);
    hipLaunchKernelGGL(k_stats, dim3(64), dim3(256), 0, stream, A, g1, be1, scsh1);
    hipLaunchKernelGGL(k_bn, dim3((NPIX_ * 64 / 4) / 256), dim3(256), 0, stream,
                       A, scsh1, 1);
    hipLaunchKernelGGL(k_offconv, dim3(288), dim3(256), 0, stream, A, ow, ob, offb);
    hipLaunchKernelGGL(k_deform, dim3(NPIX_ / 64), dim3(256), 0, stream,
                       A, offb, wk, beff, out);
    hipLaunchKernelGGL(k_stats, dim3(64), dim3(256), 0, stream, out, g2, be2, scsh2);
    hipLaunchKernelGGL(k_bn, dim3((NPIX_ * 64 / 4) / 256), dim3(256), 0, stream,
                       out, scsh2, 0);
}